// Round 4
// baseline (3085.404 us; speedup 1.0000x reference)
//
#include <hip/hip_runtime.h>
#include <hip/hip_bf16.h>

// GQA + fused QK-RMSNorm, MI355X gfx950. Round 4.
//  * attn rebuilt on mfma_f32_32x32x16_bf16: tau-permuted K rows in LDS make
//    the QK S^T C-layout == PV B-fragment layout (P never leaves registers,
//    all MFMA at full K=32-class efficiency); V pre-transposed in HBM by the
//    V-GEMM epilogue and staged via global_load_lds (no VALU transpose).
//  * GEMMs intentionally unchanged from round 3 (attribution + to surface
//    their counters in next round's top-5).

typedef short short8 __attribute__((ext_vector_type(8)));
typedef short8 short8a __attribute__((may_alias));
typedef float f32x4 __attribute__((ext_vector_type(4)));
typedef float f32x16 __attribute__((ext_vector_type(16)));
typedef float float4v __attribute__((ext_vector_type(4)));
typedef unsigned int uinta __attribute__((may_alias));
typedef unsigned short u16;

__device__ __forceinline__ u16 f2bf(float x) {          // RNE f32 -> bf16 bits
    unsigned u = __float_as_uint(x);
    u += 0x7fffu + ((u >> 16) & 1u);
    return (u16)(u >> 16);
}
__device__ __forceinline__ float bf2f(u16 b) {
    return __uint_as_float(((unsigned)b) << 16);
}
__device__ __forceinline__ unsigned pk2bf(float lo, float hi) {
    float2 t; t.x = lo; t.y = hi;                        // x -> low 16 bits
    __hip_bfloat162 h = __float22bfloat162_rn(t);        // v_cvt_pk_bf16_f32
    union { __hip_bfloat162 h; unsigned u; } c; c.h = h;
    return c.u;
}
__device__ __forceinline__ void lds_load16(void* lds, const void* g) {
    __builtin_amdgcn_global_load_lds(
        (__attribute__((address_space(1))) unsigned int*)g,
        (__attribute__((address_space(3))) unsigned int*)lds, 16, 0, 0);
}

// --------------------------------------------------------------------------
__global__ void detect_dtype(const unsigned* __restrict__ q, int* __restrict__ flag)
{
    unsigned bits = q[threadIdx.x];
    unsigned e = (bits >> 23) & 0xffu;
    bool sane = (e >= 90u && e <= 160u);
    unsigned long long m = __ballot(sane);
    if (threadIdx.x == 0) *flag = (__popcll(m) >= 48) ? 1 : 0;
}

// --------------------------------------------------------------------------
// GEMM: C[M,N] = A[M,K]*B[N,K]^T. o_mode: 0 = bf16, 1 = flag dtype,
// 2 = V^T store (bf16 ws, layout [(b*4+kvh)*128+d][s], s-stride 2048).
#define BN 128
#define BK 32

template<int RT>
__global__ __launch_bounds__(256)
void gemm_bt(const void* __restrict__ Ap, const void* __restrict__ Bp,
             void* __restrict__ Cp, const int* __restrict__ flagp,
             int M, int N, int K, int a_mode, int b_mode, int o_mode)
{
    constexpr int BM = RT * 32;
    __shared__ __attribute__((aligned(16))) u16 As[BM * BK];
    __shared__ __attribute__((aligned(16))) u16 Bs[BN * BK];
    const int f     = *flagp;
    const bool af32 = a_mode && f;
    const bool bf32 = b_mode && f;
    const bool of32 = (o_mode == 1) && f;
    const int tid  = threadIdx.x;
    const int wave = tid >> 6;
    const int lane = tid & 63;
    const int lrow = lane & 15;
    const int quad = lane >> 4;
    const int wm   = (wave >> 1) * (RT * 16);
    const int wn   = (wave & 1) * 64;
    const int m0   = blockIdx.y * BM;
    const int n0   = blockIdx.x * BN;
    const int sel  = (lrow >> 1) & 3;

    f32x4 acc[RT][4] = {};

    for (int k0 = 0; k0 < K; k0 += BK) {
        __syncthreads();
        if (!af32) {
            for (int p = 0; p < RT / 2; ++p) {
                int seg = wave * (RT / 2) + p;
                int row = seg * 16 + (lane >> 2);
                int gch = (lane & 3) ^ ((row >> 1) & 3);
                lds_load16(&As[seg * 16 * BK],
                           (const u16*)Ap + (size_t)(m0 + row) * K + k0 + gch * 8);
            }
        } else {
            for (int it = 0; it < RT / 2; ++it) {
                int idx = tid + it * 256;
                int row = idx >> 2;
                int c   = idx & 3;
                int gch = c ^ ((row >> 1) & 3);
                const float* gp = (const float*)Ap + (size_t)(m0 + row) * K + k0 + gch * 8;
                float4v x0 = *(const float4v*)gp;
                float4v x1 = *(const float4v*)(gp + 4);
                short8 v;
                for (int i = 0; i < 4; ++i) { v[i] = (short)f2bf(x0[i]); v[i + 4] = (short)f2bf(x1[i]); }
                *(short8a*)(&As[row * BK + c * 8]) = v;
            }
        }
        if (!bf32) {
            for (int p = 0; p < 2; ++p) {
                int seg = wave * 2 + p;
                int row = seg * 16 + (lane >> 2);
                int gch = (lane & 3) ^ ((row >> 1) & 3);
                lds_load16(&Bs[seg * 16 * BK],
                           (const u16*)Bp + (size_t)(n0 + row) * K + k0 + gch * 8);
            }
        } else {
            for (int it = 0; it < 2; ++it) {
                int idx = tid + it * 256;
                int row = idx >> 2;
                int c   = idx & 3;
                int gch = c ^ ((row >> 1) & 3);
                const float* gp = (const float*)Bp + (size_t)(n0 + row) * K + k0 + gch * 8;
                float4v x0 = *(const float4v*)gp;
                float4v x1 = *(const float4v*)(gp + 4);
                short8 v;
                for (int i = 0; i < 4; ++i) { v[i] = (short)f2bf(x0[i]); v[i + 4] = (short)f2bf(x1[i]); }
                *(short8a*)(&Bs[row * BK + c * 8]) = v;
            }
        }
        __builtin_amdgcn_s_waitcnt(0);
        __syncthreads();

        short8 afr[RT], bfr[4];
        for (int i = 0; i < RT; ++i)
            afr[i] = *(const short8a*)(&As[(wm + i * 16 + lrow) * BK + (quad ^ sel) * 8]);
        for (int j = 0; j < 4; ++j)
            bfr[j] = *(const short8a*)(&Bs[(wn + j * 16 + lrow) * BK + (quad ^ sel) * 8]);
        for (int i = 0; i < RT; ++i)
            for (int j = 0; j < 4; ++j)
                acc[i][j] = __builtin_amdgcn_mfma_f32_16x16x32_bf16(afr[i], bfr[j], acc[i][j], 0, 0, 0);
    }

    for (int i = 0; i < RT; ++i)
        for (int j = 0; j < 4; ++j)
            for (int r = 0; r < 4; ++r) {
                int row = m0 + wm + i * 16 + quad * 4 + r;
                int col = n0 + wn + j * 16 + lrow;
                float v = acc[i][j][r];
                if (o_mode == 2) {
                    // V^T: [(b*4+kvh)*128 + d][s], b=row>>11, s=row&2047
                    size_t fidx = ((size_t)(((row >> 11) * 4 + (col >> 7)) * 128
                                   + (col & 127))) * 2048 + (row & 2047);
                    ((u16*)Cp)[fidx] = f2bf(v);
                } else {
                    size_t idx = (size_t)row * N + col;
                    if (of32) ((float*)Cp)[idx] = v;
                    else      ((u16*)Cp)[idx]   = f2bf(v);
                }
            }
}

// --------------------------------------------------------------------------
__global__ __launch_bounds__(256)
void rmsnorm128v(u16* __restrict__ X, const void* __restrict__ w,
                 const int* __restrict__ flagp, float outscale)
{
    const int f = *flagp;
    int t     = blockIdx.x * 256 + threadIdx.x;
    int chunk = t >> 4;
    int l16   = t & 15;
    u16* xp = X + (size_t)chunk * 128 + l16 * 8;
    short8 xv = *(const short8a*)xp;
    float xs[8]; float ss = 0.f;
    for (int i = 0; i < 8; ++i) { xs[i] = bf2f((u16)xv[i]); ss += xs[i] * xs[i]; }
    ss += __shfl_xor(ss, 1); ss += __shfl_xor(ss, 2);
    ss += __shfl_xor(ss, 4); ss += __shfl_xor(ss, 8);
    float inv = outscale * rsqrtf(ss * (1.0f / 128.0f) + 1e-6f);
    float ws[8];
    if (f) {
        float4v w0 = ((const float4v*)w)[l16 * 2];
        float4v w1 = ((const float4v*)w)[l16 * 2 + 1];
        for (int i = 0; i < 4; ++i) { ws[i] = w0[i]; ws[i + 4] = w1[i]; }
    } else {
        short8 wv = ((const short8a*)w)[l16];
        for (int i = 0; i < 8; ++i) ws[i] = bf2f((u16)wv[i]);
    }
    short8 o;
    for (int i = 0; i < 8; ++i) o[i] = (short)f2bf(xs[i] * inv * ws[i]);
    *(short8a*)xp = o;
}

// --------------------------------------------------------------------------
// Flash attention on 32x32x16 MFMA. Block = (32 q-rows, kvh, b); wave g ->
// head kvh*4+g. Q pre-scaled by 1/sqrt(128)*log2e; fixed-max softmax.
//
// K rows staged tau-PERMUTED: LDS row m holds K[t0 + (m&~31) + tau(m&31)],
// tau(m') = 16*(m'>>4) + 8*((m'>>2)&1) + 4*((m'>>3)&1) + (m'&3).
// Then the QK S^T C-layout regs (lane: q=lane&31, L=lane>>5; reg r ->
// t = 32*n32 + 16*(r>>3) + 8*L + (r&7)) are EXACTLY the PV B-fragment
// (B[k=L*8+j][n=q]) for k-block T = t0+32*n32+16*kb2 -> P stays in regs.
// V^T pre-transposed in HBM ([(b*4+kvh)*128+d][s]); both tiles staged by
// global_load_lds with chunk-XOR swizzle (slot = chunk ^ (row&7)).

__global__ __launch_bounds__(256)
void attn_fused(const u16* __restrict__ Q, const u16* __restrict__ Kb,
                const u16* __restrict__ Vt, u16* __restrict__ O,
                int Sq, int Skv)
{
    __shared__ __attribute__((aligned(16))) u16 Ks[64 * 128];   // [t'][d] swizzled
    __shared__ __attribute__((aligned(16))) u16 Vs[128 * 64];   // [d][t] swizzled
    const int qt   = blockIdx.x;
    const int kvh  = blockIdx.y;
    const int b    = blockIdx.z;
    const int tid  = threadIdx.x;
    const int wave = tid >> 6;
    const int lane = tid & 63;
    const int q    = lane & 31;
    const int L    = lane >> 5;
    const int h    = kvh * 4 + wave;
    const int q0   = qt * 32;

    // Q B-frags: qf[kd][j] = Q[q0+q][h*128 + kd*16 + L*8 + j]
    short8 qf[8];
    {
        const u16* qp = Q + (size_t)(b * Sq + q0 + q) * 2048 + h * 128 + L * 8;
        for (int kd = 0; kd < 8; ++kd) qf[kd] = *(const short8a*)(qp + kd * 16);
    }

    float lsum = 0.f;
    f32x16 oacc[4] = {};

    // staging addresses (constant across tiles except t0)
    const int krow  = wave * 16 + (lane >> 4);        // covers rows wave*16..+15 over p
    const int kch   = lane & 15;
    const int vrow  = wave * 32 + (lane >> 3);        // covers rows wave*32..+31 over p
    const int vch   = lane & 7;
    const u16* kbase = Kb + (size_t)b * Skv * 512 + kvh * 128;
    const u16* vbase = Vt + (size_t)((b * 4 + kvh) * 128) * 2048;

    for (int t0 = 0; t0 < Skv; t0 += 64) {
        __syncthreads();
        // K: 16 passes of 4 rows; wave w does ldsrows [w*16, w*16+16)
        for (int p = 0; p < 4; ++p) {
            int lr  = krow + p * 4 - ((lane >> 4) ? 0 : 0);   // ldsrow
            int ldsrow = wave * 16 + p * 4 + (lane >> 4);
            (void)lr;
            int tl  = (ldsrow & 32) + (((ldsrow >> 4) & 1) << 4)
                    + (((ldsrow >> 2) & 1) << 3) + (((ldsrow >> 3) & 1) << 2)
                    + (ldsrow & 3);
            int gch = kch ^ (ldsrow & 7);
            lds_load16(&Ks[(wave * 16 + p * 4) * 128],
                       kbase + (size_t)(t0 + tl) * 512 + gch * 8);
        }
        // Vt: 16 passes of 8 rows; wave w does rows [w*32, w*32+32)
        for (int p = 0; p < 4; ++p) {
            int drow = wave * 32 + p * 8 + (lane >> 3);
            int gch  = vch ^ (drow & 7);
            lds_load16(&Vs[(wave * 32 + p * 8) * 64],
                       vbase + (size_t)drow * 2048 + t0 + gch * 8);
        }
        __builtin_amdgcn_s_waitcnt(0);
        __syncthreads();

        for (int n32 = 0; n32 < 2; ++n32) {
            // QK: S^T 32t x 32q
            f32x16 sacc = {};
            for (int kd = 0; kd < 8; ++kd) {
                short8 kf = *(const short8a*)(
                    &Ks[(n32 * 32 + q) * 128 + (((kd * 2 + L) ^ (lane & 7)) * 8)]);
                sacc = __builtin_amdgcn_mfma_f32_32x32x16_bf16(kf, qf[kd], sacc, 0, 0, 0);
            }
            // exp2 -> P B-frags (register-direct), PV
            for (int kb2 = 0; kb2 < 2; ++kb2) {
                float p0 = exp2f(sacc[kb2 * 8 + 0]), p1 = exp2f(sacc[kb2 * 8 + 1]);
                float p2 = exp2f(sacc[kb2 * 8 + 2]), p3 = exp2f(sacc[kb2 * 8 + 3]);
                float p4 = exp2f(sacc[kb2 * 8 + 4]), p5 = exp2f(sacc[kb2 * 8 + 5]);
                float p6 = exp2f(sacc[kb2 * 8 + 6]), p7 = exp2f(sacc[kb2 * 8 + 7]);
                lsum += ((p0 + p1) + (p2 + p3)) + ((p4 + p5) + (p6 + p7));
                union { short8 s; unsigned u[4]; } pf;
                pf.u[0] = pk2bf(p0, p1); pf.u[1] = pk2bf(p2, p3);
                pf.u[2] = pk2bf(p4, p5); pf.u[3] = pk2bf(p6, p7);
                for (int dblk = 0; dblk < 4; ++dblk) {
                    short8 vf = *(const short8a*)(
                        &Vs[(dblk * 32 + q) * 64
                            + (((n32 * 4 + kb2 * 2 + L) ^ (lane & 7)) * 8)]);
                    oacc[dblk] = __builtin_amdgcn_mfma_f32_32x32x16_bf16(
                        vf, pf.s, oacc[dblk], 0, 0, 0);
                }
            }
        }
    }

    // lane pair (q, L) / (q, 1-L) covers all t -> one xor-32 reduce
    lsum += __shfl_xor(lsum, 32);
    float inv = 1.0f / lsum;

    // O[q0+q][h*128 + d], d = dblk*32 + 8*(r>>2) + 4*L + (r&3): 8B stores
    {
        u16* op = O + (size_t)(b * Sq + q0 + q) * 2048 + h * 128 + L * 4;
        for (int dblk = 0; dblk < 4; ++dblk)
            for (int rg = 0; rg < 4; ++rg) {
                unsigned w0 = pk2bf(oacc[dblk][rg * 4 + 0] * inv,
                                    oacc[dblk][rg * 4 + 1] * inv);
                unsigned w1 = pk2bf(oacc[dblk][rg * 4 + 2] * inv,
                                    oacc[dblk][rg * 4 + 3] * inv);
                uint2 wv; wv.x = w0; wv.y = w1;
                *(uint2*)(op + dblk * 32 + rg * 8) = wv;
            }
    }
}

// --------------------------------------------------------------------------
extern "C" void kernel_launch(void* const* d_in, const int* in_sizes, int n_in,
                              void* d_out, int out_size, void* d_ws, size_t ws_size,
                              hipStream_t stream)
{
    const int M  = in_sizes[0] / 2048;   // B*S = 8192
    const int Sq = 2048;
    const int Bb = M / Sq;

    char* ws = (char*)d_ws;
    int* flag = (int*)ws;
    u16* Qb = (u16*)(ws + 256);
    u16* Kb = (u16*)(ws + 256 + (size_t)M * 2048 * 2);
    u16* Vb = (u16*)(ws + 256 + (size_t)M * 2048 * 2 + (size_t)M * 512 * 2);
    u16* Ob = (u16*)(ws + 256 + (size_t)M * 2048 * 2 + (size_t)M * 512 * 4);

    dim3 blk(256);
    detect_dtype<<<1, 64, 0, stream>>>((const unsigned*)d_in[0], flag);
    gemm_bt<4><<<dim3(2048 / BN, M / 128), blk, 0, stream>>>(d_in[0], d_in[3], Qb, flag, M, 2048, 2048, 1, 1, 0);
    gemm_bt<2><<<dim3(512 / BN,  M / 64),  blk, 0, stream>>>(d_in[1], d_in[4], Kb, flag, M, 512, 2048, 1, 1, 0);
    // V-GEMM writes V^T directly (o_mode=2)
    gemm_bt<2><<<dim3(512 / BN,  M / 64),  blk, 0, stream>>>(d_in[2], d_in[5], Vb, flag, M, 512, 2048, 1, 1, 2);
    rmsnorm128v<<<dim3(M),     blk, 0, stream>>>(Qb, d_in[7], flag, 0.12752227653159732f);
    rmsnorm128v<<<dim3(M / 4), blk, 0, stream>>>(Kb, d_in[8], flag, 1.0f);
    attn_fused<<<dim3(Sq / 32, 4, Bb), blk, 0, stream>>>(Qb, Kb, Vb, Ob, Sq, Sq);
    gemm_bt<4><<<dim3(2048 / BN, M / 128), blk, 0, stream>>>(Ob, d_in[6], d_out, flag, M, 2048, 2048, 0, 1, 1);
}

// Round 5
// 933.603 us; speedup vs baseline: 3.3048x; 3.3048x over previous
//
#include <hip/hip_runtime.h>
#include <hip/hip_bf16.h>

// GQA + fused QK-RMSNorm, MI355X gfx950. Round 5.
// Round-4 regression root cause: adding a RUNTIME o_mode==2 (V^T scatter)
// branch to the gemm epilogue flipped the register allocator into spilling
// the K-loop accumulators (VGPR_Count 64, WRITE_SIZE 4 GB = scratch traffic,
// 1353 us/dispatch). Fix: epilogue variant is now a TEMPLATE parameter
// (if constexpr) so the hot Q/K/O-proj instantiations compile exactly like
// the fast round-3 code; only the small V-GEMM instantiates the V^T store.
// attn_fused (32x32x16, tau-permuted K, register-resident P) kept from R4.

typedef short short8 __attribute__((ext_vector_type(8)));
typedef short8 short8a __attribute__((may_alias));
typedef float f32x4 __attribute__((ext_vector_type(4)));
typedef float f32x16 __attribute__((ext_vector_type(16)));
typedef float float4v __attribute__((ext_vector_type(4)));
typedef unsigned int uinta __attribute__((may_alias));
typedef unsigned short u16;

__device__ __forceinline__ u16 f2bf(float x) {          // RNE f32 -> bf16 bits
    unsigned u = __float_as_uint(x);
    u += 0x7fffu + ((u >> 16) & 1u);
    return (u16)(u >> 16);
}
__device__ __forceinline__ float bf2f(u16 b) {
    return __uint_as_float(((unsigned)b) << 16);
}
__device__ __forceinline__ unsigned pk2bf(float lo, float hi) {
    float2 t; t.x = lo; t.y = hi;                        // x -> low 16 bits
    __hip_bfloat162 h = __float22bfloat162_rn(t);        // v_cvt_pk_bf16_f32
    union { __hip_bfloat162 h; unsigned u; } c; c.h = h;
    return c.u;
}
__device__ __forceinline__ void lds_load16(void* lds, const void* g) {
    __builtin_amdgcn_global_load_lds(
        (__attribute__((address_space(1))) unsigned int*)g,
        (__attribute__((address_space(3))) unsigned int*)lds, 16, 0, 0);
}

// --------------------------------------------------------------------------
__global__ void detect_dtype(const unsigned* __restrict__ q, int* __restrict__ flag)
{
    unsigned bits = q[threadIdx.x];
    unsigned e = (bits >> 23) & 0xffu;
    bool sane = (e >= 90u && e <= 160u);
    unsigned long long m = __ballot(sane);
    if (threadIdx.x == 0) *flag = (__popcll(m) >= 48) ? 1 : 0;
}

// --------------------------------------------------------------------------
// GEMM: C[M,N] = A[M,K]*B[N,K]^T. OT=0: normal store (o_mode: 1 = flag dtype,
// 0 = bf16). OT=1: V^T store, bf16 ws, row b*512+col, col-stride 2048 (N=512).
#define BN 128
#define BK 32

template<int RT, int OT>
__global__ __launch_bounds__(256)
void gemm_bt(const void* __restrict__ Ap, const void* __restrict__ Bp,
             void* __restrict__ Cp, const int* __restrict__ flagp,
             int M, int N, int K, int a_mode, int b_mode, int o_mode)
{
    constexpr int BM = RT * 32;
    __shared__ __attribute__((aligned(16))) u16 As[BM * BK];
    __shared__ __attribute__((aligned(16))) u16 Bs[BN * BK];
    const int f     = *flagp;
    const bool af32 = a_mode && f;
    const bool bf32 = b_mode && f;
    const bool of32 = o_mode && f;
    const int tid  = threadIdx.x;
    const int wave = tid >> 6;
    const int lane = tid & 63;
    const int lrow = lane & 15;
    const int quad = lane >> 4;
    const int wm   = (wave >> 1) * (RT * 16);
    const int wn   = (wave & 1) * 64;
    const int m0   = blockIdx.y * BM;
    const int n0   = blockIdx.x * BN;
    const int sel  = (lrow >> 1) & 3;

    f32x4 acc[RT][4] = {};

    for (int k0 = 0; k0 < K; k0 += BK) {
        __syncthreads();
        if (!af32) {
            for (int p = 0; p < RT / 2; ++p) {
                int seg = wave * (RT / 2) + p;
                int row = seg * 16 + (lane >> 2);
                int gch = (lane & 3) ^ ((row >> 1) & 3);
                lds_load16(&As[seg * 16 * BK],
                           (const u16*)Ap + (size_t)(m0 + row) * K + k0 + gch * 8);
            }
        } else {
            for (int it = 0; it < RT / 2; ++it) {
                int idx = tid + it * 256;
                int row = idx >> 2;
                int c   = idx & 3;
                int gch = c ^ ((row >> 1) & 3);
                const float* gp = (const float*)Ap + (size_t)(m0 + row) * K + k0 + gch * 8;
                float4v x0 = *(const float4v*)gp;
                float4v x1 = *(const float4v*)(gp + 4);
                short8 v;
                for (int i = 0; i < 4; ++i) { v[i] = (short)f2bf(x0[i]); v[i + 4] = (short)f2bf(x1[i]); }
                *(short8a*)(&As[row * BK + c * 8]) = v;
            }
        }
        if (!bf32) {
            for (int p = 0; p < 2; ++p) {
                int seg = wave * 2 + p;
                int row = seg * 16 + (lane >> 2);
                int gch = (lane & 3) ^ ((row >> 1) & 3);
                lds_load16(&Bs[seg * 16 * BK],
                           (const u16*)Bp + (size_t)(n0 + row) * K + k0 + gch * 8);
            }
        } else {
            for (int it = 0; it < 2; ++it) {
                int idx = tid + it * 256;
                int row = idx >> 2;
                int c   = idx & 3;
                int gch = c ^ ((row >> 1) & 3);
                const float* gp = (const float*)Bp + (size_t)(n0 + row) * K + k0 + gch * 8;
                float4v x0 = *(const float4v*)gp;
                float4v x1 = *(const float4v*)(gp + 4);
                short8 v;
                for (int i = 0; i < 4; ++i) { v[i] = (short)f2bf(x0[i]); v[i + 4] = (short)f2bf(x1[i]); }
                *(short8a*)(&Bs[row * BK + c * 8]) = v;
            }
        }
        __builtin_amdgcn_s_waitcnt(0);
        __syncthreads();

        short8 afr[RT], bfr[4];
        for (int i = 0; i < RT; ++i)
            afr[i] = *(const short8a*)(&As[(wm + i * 16 + lrow) * BK + (quad ^ sel) * 8]);
        for (int j = 0; j < 4; ++j)
            bfr[j] = *(const short8a*)(&Bs[(wn + j * 16 + lrow) * BK + (quad ^ sel) * 8]);
        for (int i = 0; i < RT; ++i)
            for (int j = 0; j < 4; ++j)
                acc[i][j] = __builtin_amdgcn_mfma_f32_16x16x32_bf16(afr[i], bfr[j], acc[i][j], 0, 0, 0);
    }

    if constexpr (OT == 1) {
        // V^T epilogue: Vt[(row>>11)*512 + col][row&2047]; 4 consecutive s
        // (acc regs r=0..3) pack into one 8 B store.
        for (int i = 0; i < RT; ++i)
            for (int j = 0; j < 4; ++j) {
                int row0 = m0 + wm + i * 16 + quad * 4;
                int col  = n0 + wn + j * 16 + lrow;
                u16* vp = (u16*)Cp + ((size_t)((row0 >> 11) * 512 + col)) * 2048
                          + (row0 & 2047);
                uint2 wv;
                wv.x = pk2bf(acc[i][j][0], acc[i][j][1]);
                wv.y = pk2bf(acc[i][j][2], acc[i][j][3]);
                *(uint2*)vp = wv;
            }
    } else {
        for (int i = 0; i < RT; ++i)
            for (int j = 0; j < 4; ++j)
                for (int r = 0; r < 4; ++r) {
                    int row = m0 + wm + i * 16 + quad * 4 + r;
                    int col = n0 + wn + j * 16 + lrow;
                    size_t idx = (size_t)row * N + col;
                    float v = acc[i][j][r];
                    if (of32) ((float*)Cp)[idx] = v;
                    else      ((u16*)Cp)[idx]   = f2bf(v);
                }
    }
}

// --------------------------------------------------------------------------
__global__ __launch_bounds__(256)
void rmsnorm128v(u16* __restrict__ X, const void* __restrict__ w,
                 const int* __restrict__ flagp, float outscale)
{
    const int f = *flagp;
    int t     = blockIdx.x * 256 + threadIdx.x;
    int chunk = t >> 4;
    int l16   = t & 15;
    u16* xp = X + (size_t)chunk * 128 + l16 * 8;
    short8 xv = *(const short8a*)xp;
    float xs[8]; float ss = 0.f;
    for (int i = 0; i < 8; ++i) { xs[i] = bf2f((u16)xv[i]); ss += xs[i] * xs[i]; }
    ss += __shfl_xor(ss, 1); ss += __shfl_xor(ss, 2);
    ss += __shfl_xor(ss, 4); ss += __shfl_xor(ss, 8);
    float inv = outscale * rsqrtf(ss * (1.0f / 128.0f) + 1e-6f);
    float ws[8];
    if (f) {
        float4v w0 = ((const float4v*)w)[l16 * 2];
        float4v w1 = ((const float4v*)w)[l16 * 2 + 1];
        for (int i = 0; i < 4; ++i) { ws[i] = w0[i]; ws[i + 4] = w1[i]; }
    } else {
        short8 wv = ((const short8a*)w)[l16];
        for (int i = 0; i < 8; ++i) ws[i] = bf2f((u16)wv[i]);
    }
    short8 o;
    for (int i = 0; i < 8; ++i) o[i] = (short)f2bf(xs[i] * inv * ws[i]);
    *(short8a*)xp = o;
}

// --------------------------------------------------------------------------
// Flash attention on 32x32x16 MFMA (unchanged from round 4; correct there).
__global__ __launch_bounds__(256)
void attn_fused(const u16* __restrict__ Q, const u16* __restrict__ Kb,
                const u16* __restrict__ Vt, u16* __restrict__ O,
                int Sq, int Skv)
{
    __shared__ __attribute__((aligned(16))) u16 Ks[64 * 128];   // [t'][d] swizzled
    __shared__ __attribute__((aligned(16))) u16 Vs[128 * 64];   // [d][t] swizzled
    const int qt   = blockIdx.x;
    const int kvh  = blockIdx.y;
    const int b    = blockIdx.z;
    const int tid  = threadIdx.x;
    const int wave = tid >> 6;
    const int lane = tid & 63;
    const int q    = lane & 31;
    const int L    = lane >> 5;
    const int h    = kvh * 4 + wave;
    const int q0   = qt * 32;

    short8 qf[8];   // B-frag: Q[q0+q][h*128 + kd*16 + L*8 + j]
    {
        const u16* qp = Q + (size_t)(b * Sq + q0 + q) * 2048 + h * 128 + L * 8;
        for (int kd = 0; kd < 8; ++kd) qf[kd] = *(const short8a*)(qp + kd * 16);
    }

    float lsum = 0.f;
    f32x16 oacc[4] = {};

    const int kch = lane & 15;
    const int vch = lane & 7;
    const u16* kbase = Kb + (size_t)b * Skv * 512 + kvh * 128;
    const u16* vbase = Vt + (size_t)((b * 4 + kvh) * 128) * 2048;

    for (int t0 = 0; t0 < Skv; t0 += 64) {
        __syncthreads();
        // K tile: tau-permuted rows, chunk-XOR swizzle (slot = chunk^(row&7))
        for (int p = 0; p < 4; ++p) {
            int ldsrow = wave * 16 + p * 4 + (lane >> 4);
            int tl  = (ldsrow & 32) + (((ldsrow >> 4) & 1) << 4)
                    + (((ldsrow >> 2) & 1) << 3) + (((ldsrow >> 3) & 1) << 2)
                    + (ldsrow & 3);
            int gch = kch ^ (ldsrow & 7);
            lds_load16(&Ks[(wave * 16 + p * 4) * 128],
                       kbase + (size_t)(t0 + tl) * 512 + gch * 8);
        }
        // V^T tile from HBM (pre-transposed by V-GEMM epilogue)
        for (int p = 0; p < 4; ++p) {
            int drow = wave * 32 + p * 8 + (lane >> 3);
            int gch  = vch ^ (drow & 7);
            lds_load16(&Vs[(wave * 32 + p * 8) * 64],
                       vbase + (size_t)drow * 2048 + t0 + gch * 8);
        }
        __builtin_amdgcn_s_waitcnt(0);
        __syncthreads();

        for (int n32 = 0; n32 < 2; ++n32) {
            f32x16 sacc = {};
            for (int kd = 0; kd < 8; ++kd) {
                short8 kf = *(const short8a*)(
                    &Ks[(n32 * 32 + q) * 128 + (((kd * 2 + L) ^ (lane & 7)) * 8)]);
                sacc = __builtin_amdgcn_mfma_f32_32x32x16_bf16(kf, qf[kd], sacc, 0, 0, 0);
            }
            for (int kb2 = 0; kb2 < 2; ++kb2) {
                float p0 = exp2f(sacc[kb2 * 8 + 0]), p1 = exp2f(sacc[kb2 * 8 + 1]);
                float p2 = exp2f(sacc[kb2 * 8 + 2]), p3 = exp2f(sacc[kb2 * 8 + 3]);
                float p4 = exp2f(sacc[kb2 * 8 + 4]), p5 = exp2f(sacc[kb2 * 8 + 5]);
                float p6 = exp2f(sacc[kb2 * 8 + 6]), p7 = exp2f(sacc[kb2 * 8 + 7]);
                lsum += ((p0 + p1) + (p2 + p3)) + ((p4 + p5) + (p6 + p7));
                union { short8 s; unsigned u[4]; } pf;
                pf.u[0] = pk2bf(p0, p1); pf.u[1] = pk2bf(p2, p3);
                pf.u[2] = pk2bf(p4, p5); pf.u[3] = pk2bf(p6, p7);
                for (int dblk = 0; dblk < 4; ++dblk) {
                    short8 vf = *(const short8a*)(
                        &Vs[(dblk * 32 + q) * 64
                            + (((n32 * 4 + kb2 * 2 + L) ^ (lane & 7)) * 8)]);
                    oacc[dblk] = __builtin_amdgcn_mfma_f32_32x32x16_bf16(
                        vf, pf.s, oacc[dblk], 0, 0, 0);
                }
            }
        }
    }

    lsum += __shfl_xor(lsum, 32);
    float inv = 1.0f / lsum;

    {
        u16* op = O + (size_t)(b * Sq + q0 + q) * 2048 + h * 128 + L * 4;
        for (int dblk = 0; dblk < 4; ++dblk)
            for (int rg = 0; rg < 4; ++rg) {
                unsigned w0 = pk2bf(oacc[dblk][rg * 4 + 0] * inv,
                                    oacc[dblk][rg * 4 + 1] * inv);
                unsigned w1 = pk2bf(oacc[dblk][rg * 4 + 2] * inv,
                                    oacc[dblk][rg * 4 + 3] * inv);
                uint2 wv; wv.x = w0; wv.y = w1;
                *(uint2*)(op + dblk * 32 + rg * 8) = wv;
            }
    }
}

// --------------------------------------------------------------------------
extern "C" void kernel_launch(void* const* d_in, const int* in_sizes, int n_in,
                              void* d_out, int out_size, void* d_ws, size_t ws_size,
                              hipStream_t stream)
{
    const int M  = in_sizes[0] / 2048;   // B*S = 8192
    const int Sq = 2048;
    const int Bb = M / Sq;

    char* ws = (char*)d_ws;
    int* flag = (int*)ws;
    u16* Qb = (u16*)(ws + 256);
    u16* Kb = (u16*)(ws + 256 + (size_t)M * 2048 * 2);
    u16* Vb = (u16*)(ws + 256 + (size_t)M * 2048 * 2 + (size_t)M * 512 * 2);
    u16* Ob = (u16*)(ws + 256 + (size_t)M * 2048 * 2 + (size_t)M * 512 * 4);

    dim3 blk(256);
    detect_dtype<<<1, 64, 0, stream>>>((const unsigned*)d_in[0], flag);
    gemm_bt<4,0><<<dim3(2048 / BN, M / 128), blk, 0, stream>>>(d_in[0], d_in[3], Qb, flag, M, 2048, 2048, 1, 1, 0);
    gemm_bt<2,0><<<dim3(512 / BN,  M / 64),  blk, 0, stream>>>(d_in[1], d_in[4], Kb, flag, M, 512, 2048, 1, 1, 0);
    // V-GEMM writes V^T directly (compile-time OT=1 epilogue)
    gemm_bt<2,1><<<dim3(512 / BN,  M / 64),  blk, 0, stream>>>(d_in[2], d_in[5], Vb, flag, M, 512, 2048, 1, 1, 0);
    rmsnorm128v<<<dim3(M),     blk, 0, stream>>>(Qb, d_in[7], flag, 0.12752227653159732f);
    rmsnorm128v<<<dim3(M / 4), blk, 0, stream>>>(Kb, d_in[8], flag, 1.0f);
    attn_fused<<<dim3(Sq / 32, 4, Bb), blk, 0, stream>>>(Qb, Kb, Vb, Ob, Sq, Sq);
    gemm_bt<4,0><<<dim3(2048 / BN, M / 128), blk, 0, stream>>>(Ob, d_in[6], d_out, flag, M, 2048, 2048, 0, 1, 1);
}